// Round 4
// baseline (1002.952 us; speedup 1.0000x reference)
//
#include <hip/hip_runtime.h>

#define NTOK 49
#define CDIM 96
#define NH   3
#define HD   32
#define TS   52          // transposed row stride in shorts (104 B, 8B-aligned)

typedef __bf16 bf16x8 __attribute__((ext_vector_type(8)));
typedef float f32x4 __attribute__((ext_vector_type(4)));
typedef unsigned short u16;

__device__ __forceinline__ u16 f2bf(float f) {
  union { __bf16 h; u16 u; } v; v.h = (__bf16)f; return v.u;   // HW v_cvt (RNE)
}
__device__ __forceinline__ float bf2f(u16 h) {
  union { unsigned u; float f; } v; v.u = ((unsigned)h) << 16; return v.f;
}

// ---------------------------------------------------------------------------
// Prep kernel: fp32 weights -> fused/transposed bf16 weights + rpb f32 table.
//   wsS shorts:
//   [     0..27648)  W1cat_t [288][96] = [wq_sp | wk_sp | wv]^T
//   [ 27648..46080)  W2cat_t [192][96] = per-head [q|k] slices of wq,wk
//   [ 46080..55296)  W1b_t   [96][96]  = (w_ps @ Wp_top)^T
//   [ 55296..64512)  W2b_t   [96][96]  = (w_pc @ Wp_bot)^T
//   [ 64512..73728)  Wpb_t   [96][96]  = Wp_bot^T
//   wsB floats @byte 147456:
//   [0..96)       bias_all = b_ps@Wp_top + b_pc@Wp_bot + b_proj
//   [96..9504)    rpbf [3][49][64] (cols 49..63 = 0)
// ---------------------------------------------------------------------------
__global__ void prep_weights(const float* __restrict__ wq,
                             const float* __restrict__ wk,
                             const float* __restrict__ wv,
                             const float* __restrict__ wq_sp,
                             const float* __restrict__ wk_sp,
                             const float* __restrict__ w_ps,
                             const float* __restrict__ b_ps,
                             const float* __restrict__ w_pc,
                             const float* __restrict__ b_pc,
                             const float* __restrict__ w_proj,
                             const float* __restrict__ b_proj,
                             const float* __restrict__ rpb,
                             unsigned short* __restrict__ wsS,
                             float* __restrict__ wsB)
{
  const int g0 = blockIdx.x * blockDim.x + threadIdx.x;
  const int gs = gridDim.x * blockDim.x;
  const int TOT = 73728 + 96 + 3*49*64;
  for (int idx = g0; idx < TOT; idx += gs) {
    if (idx < 27648) {
      int o = idx / 96, i = idx % 96;
      float v;
      if (o < 96)       v = wq_sp[i*96 + o];
      else if (o < 192) v = wk_sp[i*96 + (o-96)];
      else              v = wv  [i*96 + (o-192)];
      wsS[idx] = f2bf(v);
    } else if (idx < 46080) {
      int j = idx - 27648, o = j / 96, i = j % 96;
      int h = o >> 6, cc = o & 63;
      wsS[idx] = f2bf((cc < 32) ? wq[i*96 + h*32 + cc] : wk[i*96 + h*32 + (cc-32)]);
    } else if (idx < 55296) {
      int j = idx - 46080, o = j / 96, i = j % 96;
      float a = 0.f;
      for (int k = 0; k < 96; ++k) a += w_ps[i*96+k] * w_proj[k*96+o];
      wsS[idx] = f2bf(a);
    } else if (idx < 64512) {
      int j = idx - 55296, o = j / 96, i = j % 96;
      float a = 0.f;
      for (int k = 0; k < 96; ++k) a += w_pc[i*96+k] * w_proj[(96+k)*96+o];
      wsS[idx] = f2bf(a);
    } else if (idx < 73728) {
      int j = idx - 64512, o = j / 96, i = j % 96;
      wsS[idx] = f2bf(w_proj[(96+i)*96 + o]);
    } else if (idx < 73824) {
      int o = idx - 73728;
      float a = b_proj[o];
      for (int k = 0; k < 96; ++k) {
        a += b_ps[k] * w_proj[k*96+o];
        a += b_pc[k] * w_proj[(96+k)*96+o];
      }
      wsB[o] = a;
    } else {
      int j = idx - 73824;
      int h = j / 3136, rr = (j % 3136) / 64, cc = j % 64;
      float v = 0.f;
      if (cc < NTOK) {
        const int ridx = (rr/7 - cc/7 + 6)*13 + (rr%7 - cc%7 + 6);
        v = rpb[ridx*NH + h];
      }
      wsB[96 + j] = v;
    }
  }
}

// ---------------------------------------------------------------------------
// Fused window kernel, round 3 (resubmit with D-pad init fix).
// LDS (shorts), total 27232 = 54464 B -> 3 blocks/CU:
//   X_O  = 0     [49][96]  x -> q (in place, own-wave rows) -> sp
//   V_O  = 4704  [49][96]  v -> (after J) outp
//   QT_O = 9408  [96][52]  qs^T -> (after D) xc row-major [49][96]
//   KT_O = 14400 [96][52]  ks^T -> probs buf B (h0,h2) -> gelu [49][96]
//   K_O  = 19392 [49][96]  k
//   SC_O = 24096 3136      cattn [96][32] -> probs buf A (h1)
// Transposed qs/ks make D's fragments contiguous (2 MFMA + A-side k-mask);
// row pads (tokens 49..51) are ZEROED at BI store time so D's B-side k=49..51
// reads are 0, never uninitialized LDS (0 x NaN hazard). Reads beyond 52-short
// rows alias the next row / adjacent region = initialized finite bf16, and
// carry A=0. Double-buffered probs let PV(h) overlap QK^T(h+1). 14 barriers.
// ---------------------------------------------------------------------------
__global__ __launch_bounds__(256, 3) void winattn_v4(
    const float* __restrict__ x,
    const float* __restrict__ bq,
    const float* __restrict__ bk,
    const float* __restrict__ bv,
    const float* __restrict__ conv1w,   // [9][96]
    const float* __restrict__ conv2w,   // [9][96]
    const unsigned short* __restrict__ wcat1,    // [288][96] bf16
    const unsigned short* __restrict__ wcat2,    // [192][96] bf16
    const unsigned short* __restrict__ w1b,      // [96][96] bf16
    const unsigned short* __restrict__ w2b,      // [96][96] bf16
    const unsigned short* __restrict__ wpb,      // [96][96] bf16
    const float* __restrict__ bias_all,          // [96]
    const float* __restrict__ rpbf,              // [3][49][64] f32
    float* __restrict__ out)
{
  __shared__ __align__(16) u16 sm[27232];   // 54464 B
  const int tid = threadIdx.x;
  const int blk = blockIdx.x;
  enum { X_O = 0, V_O = 4704, QT_O = 9408, KT_O = 14400,
         K_O = 19392, SC_O = 24096 };
  const float SCALE = 0.17677669529663687f;

  const int w  = tid >> 6;    // wave id = token m-tile
  const int l  = tid & 63;
  const int lr = l & 15;      // fragment row / col index
  const int lg = l >> 4;      // lane group

  // ---- A: load x (fp32 -> bf16 LDS) ----
  {
    const float* xg = x + (size_t)blk * 4704;
    for (int i = tid; i < 1176; i += 256) {
      const float4 v = *(const float4*)&xg[i*4];
      union { u16 s[4]; uint2 u; } p;
      p.s[0] = f2bf(v.x); p.s[1] = f2bf(v.y); p.s[2] = f2bf(v.z); p.s[3] = f2bf(v.w);
      *(uint2*)&sm[X_O + i*4] = p.u;
    }
  }
  __syncthreads();

  // ---- BI (MFMA): 30 tiles: qs^T,ks^T,v, q(->X in place),k ----
  {
    const int xrow = X_O + (16*w + lr)*96 + lg*8;
    const bf16x8 a0 = *(const bf16x8*)&sm[xrow];
    const bf16x8 a1 = *(const bf16x8*)&sm[xrow + 32];
    const bf16x8 a2 = *(const bf16x8*)&sm[xrow + 64];
    const int t0 = 16*w + 4*lg;                  // token group for epilogue
    for (int t = 0; t < 30; ++t) {
      const u16* wsrc = (t < 18) ? &wcat1[(16*t + lr)*96]
                                 : &wcat2[(16*(t-18) + lr)*96];
      const bf16x8 b0 = *(const bf16x8*)&wsrc[lg*8];
      const bf16x8 b1 = *(const bf16x8*)&wsrc[32 + lg*8];
      const bf16x8 b2 = *(const bf16x8*)&wsrc[64 + lg*8];
      f32x4 acc = {0.f, 0.f, 0.f, 0.f};
      acc = __builtin_amdgcn_mfma_f32_16x16x32_bf16(a0, b0, acc, 0, 0, 0);
      acc = __builtin_amdgcn_mfma_f32_16x16x32_bf16(a1, b1, acc, 0, 0, 0);
      acc = __builtin_amdgcn_mfma_f32_16x16x32_bf16(a2, b2, acc, 0, 0, 0);
      if (t < 12) {
        // transposed store: channel row, 4 consecutive tokens
        const int base = (t < 6) ? (QT_O + (16*t + lr)*TS)
                                 : (KT_O + (16*(t-6) + lr)*TS);
        u16 s0 = f2bf(acc[0]), s1 = f2bf(acc[1]), s2 = f2bf(acc[2]), s3 = f2bf(acc[3]);
        if (t0 <= 44) {
          uint2 pk; pk.x = (unsigned)s0 | ((unsigned)s1 << 16);
          pk.y = (unsigned)s2 | ((unsigned)s3 << 16);
          *(uint2*)&sm[base + t0] = pk;
        } else if (t0 == 48) {
          // token 48 + ZERO pads 49..51 (fills the 52-short row exactly;
          // D's B-side k=49..51 fragment reads must see 0, not stale LDS)
          uint2 pk; pk.x = (unsigned)s0; pk.y = 0u;
          *(uint2*)&sm[base + 48] = pk;
        }
      } else if (t < 18) {
        const int c = 16*t + lr - 192;
        const float bias = bv[c];
        #pragma unroll
        for (int r = 0; r < 4; ++r) {
          const int tok = t0 + r;
          if (tok < NTOK) sm[V_O + tok*96 + c] = f2bf(acc[r] + bias);
        }
      } else {
        const int u = t - 18, h = u >> 2;
        const bool isq = (u & 3) < 2;
        const int cc = (u & 1)*16 + lr;
        const float bias = isq ? bq[h*32 + cc] : bk[h*32 + cc];
        const int dst = (isq ? X_O : K_O) + h*32 + cc;
        #pragma unroll
        for (int r = 0; r < 4; ++r) {
          const int tok = t0 + r;
          if (tok < NTOK) sm[dst + tok*96] = f2bf(acc[r] + bias);
        }
      }
    }
  }
  __syncthreads();

  // ---- C': L2-normalize qs^T, ks^T rows in place (contiguous) ----
  if (tid < 192) {
    const int base = (tid < 96) ? (QT_O + tid*TS) : (KT_O + (tid-96)*TS);
    float ss = 0.f;
    #pragma unroll
    for (int i = 0; i < 12; ++i) {
      const uint2 uu = *(const uint2*)&sm[base + i*4];
      const float v0 = bf2f((u16)(uu.x & 0xFFFF)), v1 = bf2f((u16)(uu.x >> 16));
      const float v2 = bf2f((u16)(uu.y & 0xFFFF)), v3 = bf2f((u16)(uu.y >> 16));
      ss += v0*v0 + v1*v1 + v2*v2 + v3*v3;
    }
    { const float v = bf2f(sm[base + 48]); ss += v*v; }
    const float rn = 1.0f / fmaxf(sqrtf(ss), 1e-12f);
    #pragma unroll
    for (int i = 0; i < 12; ++i) {
      uint2 uu = *(const uint2*)&sm[base + i*4];
      const u16 o0 = f2bf(bf2f((u16)(uu.x & 0xFFFF)) * rn);
      const u16 o1 = f2bf(bf2f((u16)(uu.x >> 16)) * rn);
      const u16 o2 = f2bf(bf2f((u16)(uu.y & 0xFFFF)) * rn);
      const u16 o3 = f2bf(bf2f((u16)(uu.y >> 16)) * rn);
      uu.x = (unsigned)o0 | ((unsigned)o1 << 16);
      uu.y = (unsigned)o2 | ((unsigned)o3 << 16);
      *(uint2*)&sm[base + i*4] = uu;
    }
    sm[base + 48] = f2bf(bf2f(sm[base + 48]) * rn);
  }
  __syncthreads();

  // ---- D (MFMA): cattn logits [96][32] from contiguous ks^T/qs^T ----
  {
    union U8 { uint2 q[2]; bf16x8 v; };
    for (int jb = 0; jb < 3; ++jb) {
      const int job = w*3 + jb, rt = job >> 1, ct = job & 1, h = rt >> 1;
      const int abase = KT_O + (16*rt + lr)*TS + lg*8;
      const int bbase = QT_O + (h*32 + 16*ct + lr)*TS + lg*8;
      U8 A0, B0, A1, B1;
      A0.q[0] = *(const uint2*)&sm[abase];      A0.q[1] = *(const uint2*)&sm[abase + 4];
      B0.q[0] = *(const uint2*)&sm[bbase];      B0.q[1] = *(const uint2*)&sm[bbase + 4];
      A1.q[0] = *(const uint2*)&sm[abase + 32]; A1.q[1] = *(const uint2*)&sm[abase + 36];
      B1.q[0] = *(const uint2*)&sm[bbase + 32]; B1.q[1] = *(const uint2*)&sm[bbase + 36];
      // k-mask (A side): MFMA1 covers tokens 32+lg*8+j; valid only < 49.
      // Tokens 49..51 are zeroed pads; >=52 alias next-row data, masked here.
      if (lg == 2)      { A1.q[0].x &= 0xFFFFu; A1.q[0].y = 0u; A1.q[1].x = 0u; A1.q[1].y = 0u; }
      else if (lg == 3) { A1.q[0].x = 0u; A1.q[0].y = 0u; A1.q[1].x = 0u; A1.q[1].y = 0u; }
      f32x4 acc = {0.f, 0.f, 0.f, 0.f};
      acc = __builtin_amdgcn_mfma_f32_16x16x32_bf16(A0.v, B0.v, acc, 0, 0, 0);
      acc = __builtin_amdgcn_mfma_f32_16x16x32_bf16(A1.v, B1.v, acc, 0, 0, 0);
      #pragma unroll
      for (int r = 0; r < 4; ++r) {
        const int dq = 16*rt + lg*4 + r;
        sm[SC_O + dq*32 + 16*ct + lr] = f2bf(acc[r] * SCALE);
      }
    }
  }
  __syncthreads();

  // ---- E: softmax over e (96 rows of 32) + zero probs-buf-B pad cols ----
  if (tid < 96) {
    const int base = SC_O + tid*32;
    const int off = (tid * 5) & 31;
    float m = -1e30f;
    for (int jj = 0; jj < 32; ++jj) { const int j = (jj + off) & 31;
      m = fmaxf(m, bf2f(sm[base + j])); }
    float s = 0.f;
    for (int jj = 0; jj < 32; ++jj) { const int j = (jj + off) & 31;
      s += __expf(bf2f(sm[base + j]) - m); }
    const float inv = 1.0f / s;
    for (int jj = 0; jj < 32; ++jj) { const int j = (jj + off) & 31;
      sm[base + j] = f2bf(__expf(bf2f(sm[base + j]) - m) * inv); }
  }
  for (int zi = tid; zi < 735; zi += 256)         // KT probs pads (rows<49, cols 49..63)
    sm[KT_O + (zi/15)*64 + 49 + zi%15] = 0;
  __syncthreads();

  // ---- lambdas for spatial attention ----
  auto QKT = [&](int h, int scb) {
    const bf16x8 aq = *(const bf16x8*)&sm[X_O + (16*w + lr)*96 + h*32 + lg*8];
    #pragma unroll
    for (int nt = 0; nt < 4; ++nt) {
      const bf16x8 bk8 = *(const bf16x8*)&sm[K_O + (16*nt + lr)*96 + h*32 + lg*8];
      f32x4 acc = {0.f, 0.f, 0.f, 0.f};
      acc = __builtin_amdgcn_mfma_f32_16x16x32_bf16(aq, bk8, acc, 0, 0, 0);
      const int col = 16*nt + lr;
      #pragma unroll
      for (int r = 0; r < 4; ++r) {
        const int row = 16*w + lg*4 + r;
        const int rc = (row < 48) ? row : 48;
        const float bias = rpbf[(h*49 + rc)*64 + col];
        if (row < NTOK && col < NTOK)
          sm[scb + row*64 + col] = f2bf(acc[r] * SCALE + bias);
      }
    }
  };
  auto SMAX = [&](int scb) {
    if (tid < 196) {
      const int row = tid >> 2, p = tid & 3;
      const int cS = p * 13;
      const int cnt = (p == 3) ? 10 : 13;
      const int ro = row % cnt;
      const int base = scb + row*64 + cS;
      float m = -1e30f;
      for (int i = 0; i < cnt; ++i) {
        int j = i + ro; if (j >= cnt) j -= cnt;
        m = fmaxf(m, bf2f(sm[base + j]));
      }
      m = fmaxf(m, __shfl_xor(m, 1, 4));
      m = fmaxf(m, __shfl_xor(m, 2, 4));
      float s = 0.f;
      for (int i = 0; i < cnt; ++i) {
        int j = i + ro; if (j >= cnt) j -= cnt;
        s += __expf(bf2f(sm[base + j]) - m);
      }
      s += __shfl_xor(s, 1, 4);
      s += __shfl_xor(s, 2, 4);
      const float inv = 1.0f / s;
      for (int i = 0; i < cnt; ++i) {
        int j = i + ro; if (j >= cnt) j -= cnt;
        sm[base + j] = f2bf(__expf(bf2f(sm[base + j]) - m) * inv);
      }
    }
  };
  auto PV = [&](int h, int scb) {
    const int prow = (16*w + lr < 48) ? (16*w + lr) : 48;
    const bf16x8 ap0 = *(const bf16x8*)&sm[scb + prow*64 + lg*8];
    const bf16x8 ap1 = *(const bf16x8*)&sm[scb + prow*64 + 32 + lg*8];
    #pragma unroll
    for (int nt = 0; nt < 2; ++nt) {
      f32x4 acc = {0.f, 0.f, 0.f, 0.f};
      union { u16 u[8]; bf16x8 v; } cv;
      #pragma unroll
      for (int j = 0; j < 8; ++j)
        cv.u[j] = sm[V_O + (lg*8 + j)*96 + h*32 + 16*nt + lr];
      acc = __builtin_amdgcn_mfma_f32_16x16x32_bf16(ap0, cv.v, acc, 0, 0, 0);
      #pragma unroll
      for (int j = 0; j < 8; ++j)
        cv.u[j] = sm[V_O + (32 + lg*8 + j)*96 + h*32 + 16*nt + lr];
      acc = __builtin_amdgcn_mfma_f32_16x16x32_bf16(ap1, cv.v, acc, 0, 0, 0);
      #pragma unroll
      for (int r = 0; r < 4; ++r) {
        const int tok = 16*w + lg*4 + r;
        if (tok < NTOK) sm[X_O + tok*96 + h*32 + 16*nt + lr] = f2bf(acc[r]);
      }
    }
  };

  // ---- F (MFMA): xc = cattn @ V -> QT region row-major; + QKT head 0 ----
  {
    for (int ctile = 0; ctile < 6; ++ctile) {
      const int h = ctile >> 1;
      const bf16x8 av = *(const bf16x8*)&sm[V_O + (16*w + lr)*96 + h*32 + lg*8];
      const bf16x8 bc = *(const bf16x8*)&sm[SC_O + (16*ctile + lr)*32 + lg*8];
      f32x4 acc = {0.f, 0.f, 0.f, 0.f};
      acc = __builtin_amdgcn_mfma_f32_16x16x32_bf16(av, bc, acc, 0, 0, 0);
      #pragma unroll
      for (int r = 0; r < 4; ++r) {
        const int tok = 16*w + lg*4 + r;
        if (tok < NTOK) sm[QT_O + tok*96 + 16*ctile + lr] = f2bf(acc[r]);
      }
    }
    QKT(0, KT_O);
  }
  __syncthreads();

  SMAX(KT_O);
  if (tid >= 196) {                               // zero SC probs pads
    for (int zi = tid - 196; zi < 735; zi += 60)
      sm[SC_O + (zi/15)*64 + 49 + zi%15] = 0;
  }
  __syncthreads();

  PV(0, KT_O); QKT(1, SC_O);
  __syncthreads();
  SMAX(SC_O);
  __syncthreads();
  PV(1, SC_O); QKT(2, KT_O);
  __syncthreads();
  SMAX(KT_O);
  __syncthreads();
  PV(2, KT_O);
  __syncthreads();

  // ---- G: conv1 + exact GELU: V -> KT region row-major [49][96] ----
  for (int idx = tid; idx < 588; idx += 256) {
    const int n = idx / 12, c0 = (idx % 12) * 8;
    const int y = n / 7, xx = n % 7;
    float a[8];
    #pragma unroll
    for (int j = 0; j < 8; ++j) a[j] = 0.f;
    #pragma unroll
    for (int dy = -1; dy <= 1; ++dy) {
      const int yy = y + dy;
      if (yy < 0 || yy >= 7) continue;
      #pragma unroll
      for (int dx = -1; dx <= 1; ++dx) {
        const int x2 = xx + dx;
        if (x2 < 0 || x2 >= 7) continue;
        union { bf16x8 v; u16 u[8]; } iv;
        iv.v = *(const bf16x8*)&sm[V_O + (yy*7 + x2)*96 + c0];
        const float* wp = conv1w + ((dy+1)*3 + (dx+1))*96 + c0;
        #pragma unroll
        for (int j = 0; j < 8; ++j) a[j] += bf2f(iv.u[j]) * wp[j];
      }
    }
    union { u16 u[8]; bf16x8 v; } ov;
    #pragma unroll
    for (int j = 0; j < 8; ++j) {
      const float g = a[j];
      ov.u[j] = f2bf(0.5f * g * (1.0f + erff(g * 0.70710678118654752f)));
    }
    *(bf16x8*)&sm[KT_O + n*96 + c0] = ov.v;
  }
  __syncthreads();

  // ---- H: conv2: KT(gelu) -> V region (outp) ----
  for (int idx = tid; idx < 588; idx += 256) {
    const int n = idx / 12, c0 = (idx % 12) * 8;
    const int y = n / 7, xx = n % 7;
    float a[8];
    #pragma unroll
    for (int j = 0; j < 8; ++j) a[j] = 0.f;
    #pragma unroll
    for (int dy = -1; dy <= 1; ++dy) {
      const int yy = y + dy;
      if (yy < 0 || yy >= 7) continue;
      #pragma unroll
      for (int dx = -1; dx <= 1; ++dx) {
        const int x2 = xx + dx;
        if (x2 < 0 || x2 >= 7) continue;
        union { bf16x8 v; u16 u[8]; } iv;
        iv.v = *(const bf16x8*)&sm[KT_O + (yy*7 + x2)*96 + c0];
        const float* wp = conv2w + ((dy+1)*3 + (dx+1))*96 + c0;
        #pragma unroll
        for (int j = 0; j < 8; ++j) a[j] += bf2f(iv.u[j]) * wp[j];
      }
    }
    union { u16 u[8]; bf16x8 v; } ov;
    #pragma unroll
    for (int j = 0; j < 8; ++j) ov.u[j] = f2bf(a[j]);
    *(bf16x8*)&sm[V_O + n*96 + c0] = ov.v;
  }
  __syncthreads();

  // ---- K (MFMA): out = sp@W1b + xc@W2b + outp@Wpb + bias_all ----
  {
    f32x4 acc[6];
    #pragma unroll
    for (int t = 0; t < 6; ++t) acc[t] = (f32x4){0.f, 0.f, 0.f, 0.f};
    const int Ao[3] = { X_O, QT_O, V_O };
    const u16* const Ws[3] = { w1b, w2b, wpb };
    #pragma unroll
    for (int s = 0; s < 3; ++s) {
      const int arow = Ao[s] + (16*w + lr)*96 + lg*8;
      const bf16x8 a0 = *(const bf16x8*)&sm[arow];
      const bf16x8 a1 = *(const bf16x8*)&sm[arow + 32];
      const bf16x8 a2 = *(const bf16x8*)&sm[arow + 64];
      #pragma unroll
      for (int t = 0; t < 6; ++t) {
        const int o = 16*t + lr;
        const bf16x8 b0 = *(const bf16x8*)&Ws[s][o*96 + lg*8];
        const bf16x8 b1 = *(const bf16x8*)&Ws[s][o*96 + 32 + lg*8];
        const bf16x8 b2 = *(const bf16x8*)&Ws[s][o*96 + 64 + lg*8];
        acc[t] = __builtin_amdgcn_mfma_f32_16x16x32_bf16(a0, b0, acc[t], 0, 0, 0);
        acc[t] = __builtin_amdgcn_mfma_f32_16x16x32_bf16(a1, b1, acc[t], 0, 0, 0);
        acc[t] = __builtin_amdgcn_mfma_f32_16x16x32_bf16(a2, b2, acc[t], 0, 0, 0);
      }
    }
    float* og = out + (size_t)blk * 4704;
    #pragma unroll
    for (int t = 0; t < 6; ++t) {
      const int co = 16*t + lr;
      const float bb = bias_all[co];
      #pragma unroll
      for (int r = 0; r < 4; ++r) {
        const int tok = 16*w + lg*4 + r;
        if (tok < NTOK) og[tok*96 + co] = acc[t][r] + bb;
      }
    }
  }
}

extern "C" void kernel_launch(void* const* d_in, const int* in_sizes, int n_in,
                              void* d_out, int out_size, void* d_ws, size_t ws_size,
                              hipStream_t stream)
{
  const float* x      = (const float*)d_in[0];
  const float* rpbt   = (const float*)d_in[1];
  const float* wq     = (const float*)d_in[2];
  const float* bq     = (const float*)d_in[3];
  const float* wk     = (const float*)d_in[4];
  const float* bk     = (const float*)d_in[5];
  const float* wv     = (const float*)d_in[6];
  const float* bv     = (const float*)d_in[7];
  const float* w_ps   = (const float*)d_in[8];
  const float* b_ps   = (const float*)d_in[9];
  const float* wq_sp  = (const float*)d_in[10];
  const float* wk_sp  = (const float*)d_in[11];
  const float* w_pc   = (const float*)d_in[12];
  const float* b_pc   = (const float*)d_in[13];
  const float* conv1  = (const float*)d_in[14];
  const float* conv2  = (const float*)d_in[15];
  const float* w_proj = (const float*)d_in[16];
  const float* b_proj = (const float*)d_in[17];

  unsigned short* wsS = (unsigned short*)d_ws;
  float* wsB = (float*)((char*)d_ws + (size_t)2*73728);

  prep_weights<<<80, 256, 0, stream>>>(wq, wk, wv, wq_sp, wk_sp, w_ps, b_ps,
                                       w_pc, b_pc, w_proj, b_proj, rpbt,
                                       wsS, wsB);

  const int nblk = in_sizes[0] / (NTOK*CDIM);   // 8192 windows
  winattn_v4<<<nblk, 256, 0, stream>>>(x, bq, bk, bv, conv1, conv2,
      wsS, wsS + 27648, wsS + 46080, wsS + 55296, wsS + 64512,
      wsB, wsB + 96, (float*)d_out);
}